// Round 1
// baseline (2181.835 us; speedup 1.0000x reference)
//
#include <hip/hip_runtime.h>

// RelativePositionSDPA (Transformer-XL rel-shift attention), MI355X/gfx950.
// Round 0: correctness-first fused flash-style kernel, fp32 vector math.
//
// Shapes: Q,K,V (NH=64, S=1024, D=64) fp32; u_bias,v_bias (16,64); R (16,2048,64).
// Shift semantics (derived from the jnp reshape trick, hand-verified S=2,3):
//   u = (b > a); i = a + u; j = b - i - 1 + S*(1-u)
//   shifted[a,b] = (j < 0) ? 0 : dot(q_v[i], R[h][j])       (j==-1 only at b==a+1)
//   lower (b<=a): j = b-a-1+S in [0, S-1]; upper (b>=a+2): j = b-a-2 in [0,S-3].
// Softmax is over the FULL row (no causal mask in the reference!).

#define NHEADS 16
#define HDIM   64
#define SEQLEN 1024
#define NHTOT  64
#define MAXSEQ 2048
#define QSCALE 0.125f   // 64^-0.5

// Broadcast lane `src`'s value to all lanes via v_readlane (VALU pipe, not DS —
// keeps ~800 broadcasts/wave-tile off the LDS pipe).
__device__ __forceinline__ float lane_bcast(float v, int src) {
  return __builtin_bit_cast(float,
      __builtin_amdgcn_readlane(__builtin_bit_cast(int, v), src));
}

__global__ __launch_bounds__(256) void relpos_sdpa_kernel(
    const float* __restrict__ Q, const float* __restrict__ K,
    const float* __restrict__ V, const float* __restrict__ Ub,
    const float* __restrict__ Vb, const float* __restrict__ R,
    float* __restrict__ O)
{
  const int n    = blockIdx.y;            // n = batch*16 + head
  const int h    = n & (NHEADS - 1);      // head index
  const int lane = threadIdx.x & 63;
  const int wave = threadIdx.x >> 6;
  const int a0   = blockIdx.x * 16 + wave * 4;   // 4 query rows per wave

  const float* Qn = Q + (size_t)n * SEQLEN * HDIM;
  const float* Kn = K + (size_t)n * SEQLEN * HDIM;
  const float* Vn = V + (size_t)n * SEQLEN * HDIM;
  const float* Rh = R + (size_t)h * MAXSEQ * HDIM;

  const float ubl = Ub[h * HDIM + lane];
  const float vbl = Vb[h * HDIM + lane];

  // lane holds dimension `lane` of each q row. qv[4] = row a0+4 (upper branch
  // of row a0+3); clamped load — it is never actually selected when a0+3==S-1.
  float qu[4], qv[5];
#pragma unroll
  for (int i = 0; i < 4; ++i) {
    float q = Qn[(a0 + i) * HDIM + lane] * QSCALE;
    qu[i] = q + ubl;
    qv[i] = q + vbl;
  }
  {
    int a4 = a0 + 4; if (a4 > SEQLEN - 1) a4 = SEQLEN - 1;
    qv[4] = Qn[a4 * HDIM + lane] * QSCALE + vbl;
  }

  __shared__ float Kt[HDIM][64 + 1];  // transposed K tile, +1 pad: conflict-free
  __shared__ float Vs[64][HDIM];      // V tile, natural layout (reads along d)

  float m[4], l[4], acc[4];
#pragma unroll
  for (int i = 0; i < 4; ++i) { m[i] = -3.0e38f; l[i] = 0.f; acc[i] = 0.f; }

  for (int k0 = 0; k0 < SEQLEN; k0 += 64) {
    __syncthreads();
#pragma unroll
    for (int ii = 0; ii < 16; ++ii) {
      int row = wave * 16 + ii;   // 4 waves x 16 = 64 rows, lane = d (coalesced)
      Kt[lane][row] = Kn[(k0 + row) * HDIM + lane];
      Vs[row][lane] = Vn[(k0 + row) * HDIM + lane];
    }
    __syncthreads();

    const int b = k0 + lane;      // this lane's key/column index

    // ---- content scores: s[i] = qu[a0+i] . K[b] ----
    float s0 = 0.f, s1 = 0.f, s2 = 0.f, s3 = 0.f;
#pragma unroll
    for (int d = 0; d < HDIM; ++d) {
      float kv = Kt[d][lane];
      s0 = fmaf(lane_bcast(qu[0], d), kv, s0);
      s1 = fmaf(lane_bcast(qu[1], d), kv, s1);
      s2 = fmaf(lane_bcast(qu[2], d), kv, s2);
      s3 = fmaf(lane_bcast(qu[3], d), kv, s3);
    }
    float s[4] = {s0, s1, s2, s3};

    // ---- positional scores (shifted) ----
    const float4* Rp[4];
    bool up[4]; bool zr[4];
#pragma unroll
    for (int i = 0; i < 4; ++i) {
      int a = a0 + i;
      up[i] = (b > a);
      int j = up[i] ? (b - a - 2) : (b - a - 1 + SEQLEN);
      zr[i] = (j < 0);            // only b == a+1
      if (j < 0) j = 0;
      Rp[i] = (const float4*)(Rh + (size_t)j * HDIM);
    }
    float p0 = 0.f, p1 = 0.f, p2 = 0.f, p3 = 0.f;
#pragma unroll
    for (int d4 = 0; d4 < HDIM / 4; ++d4) {
      float4 r0 = Rp[0][d4], r1 = Rp[1][d4], r2 = Rp[2][d4], r3 = Rp[3][d4];
#pragma unroll
      for (int c = 0; c < 4; ++c) {
        int d = d4 * 4 + c;
        float q0 = lane_bcast(qv[0], d);
        float q1 = lane_bcast(qv[1], d);
        float q2 = lane_bcast(qv[2], d);
        float q3 = lane_bcast(qv[3], d);
        float q4 = lane_bcast(qv[4], d);
        p0 = fmaf(up[0] ? q1 : q0, (&r0.x)[c], p0);   // upper branch uses row a+1's qv
        p1 = fmaf(up[1] ? q2 : q1, (&r1.x)[c], p1);
        p2 = fmaf(up[2] ? q3 : q2, (&r2.x)[c], p2);
        p3 = fmaf(up[3] ? q4 : q3, (&r3.x)[c], p3);
      }
    }
    s[0] += zr[0] ? 0.f : p0;
    s[1] += zr[1] ? 0.f : p1;
    s[2] += zr[2] ? 0.f : p2;
    s[3] += zr[3] ? 0.f : p3;

    // ---- online softmax update (full-row, no mask) ----
    float pr[4];
#pragma unroll
    for (int i = 0; i < 4; ++i) {
      float sm = s[i];
#pragma unroll
      for (int off = 32; off > 0; off >>= 1)
        sm = fmaxf(sm, __shfl_xor(sm, off));
      float mnew  = fmaxf(m[i], sm);
      float alpha = __expf(m[i] - mnew);   // first tile: exp(-3e38-m) == 0
      float p     = __expf(s[i] - mnew);
      float ps = p;
#pragma unroll
      for (int off = 32; off > 0; off >>= 1)
        ps += __shfl_xor(ps, off);
      l[i]   = l[i] * alpha + ps;
      m[i]   = mnew;
      acc[i] *= alpha;
      pr[i]  = p;
    }

    // ---- PV: acc[i][lane] += sum_b p[i][b] * V[b][lane] ----
#pragma unroll
    for (int bb = 0; bb < 64; ++bb) {
      float vv = Vs[bb][lane];
      acc[0] = fmaf(lane_bcast(pr[0], bb), vv, acc[0]);
      acc[1] = fmaf(lane_bcast(pr[1], bb), vv, acc[1]);
      acc[2] = fmaf(lane_bcast(pr[2], bb), vv, acc[2]);
      acc[3] = fmaf(lane_bcast(pr[3], bb), vv, acc[3]);
    }
  }

#pragma unroll
  for (int i = 0; i < 4; ++i)
    O[((size_t)n * SEQLEN + (a0 + i)) * HDIM + lane] = acc[i] / l[i];
}

extern "C" void kernel_launch(void* const* d_in, const int* in_sizes, int n_in,
                              void* d_out, int out_size, void* d_ws, size_t ws_size,
                              hipStream_t stream) {
  const float* Q  = (const float*)d_in[0];
  const float* K  = (const float*)d_in[1];
  const float* V  = (const float*)d_in[2];
  const float* Ub = (const float*)d_in[3];  // (1,16,1,64) -> [h*64+d]
  const float* Vb = (const float*)d_in[4];
  const float* R  = (const float*)d_in[5];  // (16,2048,64)
  float* O = (float*)d_out;

  dim3 grid(SEQLEN / 16, NHTOT);  // block = 16 q-rows, grid = (64, 64)
  relpos_sdpa_kernel<<<grid, 256, 0, stream>>>(Q, K, V, Ub, Vb, R, O);
}

// Round 3
// 217.391 us; speedup vs baseline: 10.0364x; 10.0364x over previous
//
#include <hip/hip_runtime.h>

// RelativePositionSDPA — R2: fully-MFMA flash kernel, fp16 matmuls (bf16 failed
// accuracy at absmax 0.168 vs 0.095; fp16 has 8x finer rounding), fp32 softmax.
//
// Per block: one n (=batch*16+head), 64 query rows. K-loop over 16 tiles of 64 keys.
// Positional scores via a sliding band GEMM: Pb[i'][slot] = qv[a0+i'] . R[j],
// slot = j & 127 (ring; window width Mq+Bk = 128 divides S). Each iter computes
// the 64 new columns j in [delta-1, delta+62], delta = k0-a0; prologue fills
// [delta0-65, delta0-2]. Gather: shifted[a,b] = Pb[ii+u][(e-1-u)&127], e=b-a,
// u=(e>0), zero at e==1  (shift semantics verified in fp32 by the R0 kernel).

#define SQ    1024
#define HD    64
#define NHD   16
#define RMAX  2048

typedef _Float16 f16x8 __attribute__((ext_vector_type(8)));
typedef float    f32x4 __attribute__((ext_vector_type(4)));

#define MFMA16(A,B,C) __builtin_amdgcn_mfma_f32_16x16x32_f16((A),(B),(C),0,0,0)

__device__ __forceinline__ f16x8 cvt8(const float* p) {
  f16x8 r;
#pragma unroll
  for (int j = 0; j < 8; ++j) r[j] = (_Float16)p[j];
  return r;
}

__global__ __launch_bounds__(256, 2) void relpos_sdpa_mfma(
    const float* __restrict__ Q, const float* __restrict__ K,
    const float* __restrict__ V, const float* __restrict__ Ub,
    const float* __restrict__ Vb, const float* __restrict__ R,
    float* __restrict__ O)
{
  const int n    = blockIdx.x;            // grid.x = n: same-n blocks share XCD L2
  const int h    = n & (NHD - 1);
  const int a0   = blockIdx.y * 64;
  const int tid  = threadIdx.x;
  const int lane = tid & 63, wave = tid >> 6;
  const int l15  = lane & 15, quad = lane >> 4;

  const float* Qn = Q + (size_t)n * SQ * HD;
  const float* Kn = K + (size_t)n * SQ * HD;
  const float* Vn = V + (size_t)n * SQ * HD;
  const float* Rh = R + (size_t)h * RMAX * HD;

  // LDS: strides padded (72 f16 = 144 B, 132 fp32) -> <=2-way bank aliasing
  __shared__ __align__(16) _Float16 KbS[64 * 72];    // K tile  [key][d]
  __shared__ __align__(16) _Float16 VtS[64 * 72];    // V tile  [d][key] (transposed)
  __shared__ __align__(16) _Float16 RbS[64 * 72];    // R rows  [local][d]
  __shared__ __align__(16) _Float16 PsS[4 * 16 * 72];// P per wave [q][key]
  __shared__ __align__(16) float    Pb[80 * 132];    // band ring [i'][slot]

  // ---- persistent q fragments (A-layout: m=l15, k=quad*8+j, kstep*32) ----
  f16x8 quF[2], qvF[5][2];
#pragma unroll
  for (int ks = 0; ks < 2; ++ks) {
    const int db = ks * 32 + quad * 8;
    float ub[8], vb[8];
#pragma unroll
    for (int j = 0; j < 8; ++j) { ub[j] = Ub[h*HD + db + j]; vb[j] = Vb[h*HD + db + j]; }
    {
      const float* p = Qn + (size_t)(a0 + 16*wave + l15) * HD + db;
      f16x8 f;
#pragma unroll
      for (int j = 0; j < 8; ++j) f[j] = (_Float16)(p[j] * 0.125f + ub[j]);
      quF[ks] = f;
    }
#pragma unroll
    for (int rt = 0; rt < 5; ++rt) {
      int row = a0 + 16*rt + l15; if (row > SQ-1) row = SQ-1;  // pad rows: unused
      const float* p = Qn + (size_t)row * HD + db;
      f16x8 f;
#pragma unroll
      for (int j = 0; j < 8; ++j) f[j] = (_Float16)(p[j] * 0.125f + vb[j]);
      qvF[rt][ks] = f;
    }
  }

  float mrow[4], lrow[4];
  f32x4 Oacc[4];
#pragma unroll
  for (int r = 0; r < 4; ++r) { mrow[r] = -3.0e38f; lrow[r] = 0.f; }
#pragma unroll
  for (int ct = 0; ct < 4; ++ct) Oacc[ct] = (f32x4){0.f, 0.f, 0.f, 0.f};

  const int stg_row = tid >> 2, stg_cq = tid & 3;

  // stage 64 R rows (j = jstart+lr mod S), band GEMM, scatter into the ring.
  auto fill_band = [&](int jstart) {
    {
      int j = (jstart + stg_row + 2048) & (SQ - 1);
      const float* src = Rh + (size_t)j * HD + stg_cq * 16;
      *(f16x8*)&RbS[stg_row * 72 + stg_cq * 16]     = cvt8(src);
      *(f16x8*)&RbS[stg_row * 72 + stg_cq * 16 + 8] = cvt8(src + 8);
    }
    __syncthreads();   // Rb (and, in-loop, Kb/Vt) visible
    f16x8 B0 = *(const f16x8*)&RbS[(16*wave + l15) * 72 + quad * 8];
    f16x8 B1 = *(const f16x8*)&RbS[(16*wave + l15) * 72 + 32 + quad * 8];
    const int slot = (jstart + 16*wave + l15 + 2048) & 127;
#pragma unroll
    for (int rt = 0; rt < 5; ++rt) {
      f32x4 acc = (f32x4){0.f, 0.f, 0.f, 0.f};
      acc = MFMA16(qvF[rt][0], B0, acc);
      acc = MFMA16(qvF[rt][1], B1, acc);
      const int ib = (16*rt + 4*quad) * 132 + slot;
      Pb[ib]       = acc[0];
      Pb[ib + 132] = acc[1];
      Pb[ib + 264] = acc[2];
      Pb[ib + 396] = acc[3];
    }
  };

  fill_band(-a0 - 65);   // prologue: lower half of iter-0's window

  for (int k0 = 0; k0 < SQ; k0 += 64) {
    __syncthreads();   // prev-iter Pb/Vt/Ps/Rb reads done before restaging

    { // stage K tile
      const float* src = Kn + (size_t)(k0 + stg_row) * HD + stg_cq * 16;
      *(f16x8*)&KbS[stg_row * 72 + stg_cq * 16]     = cvt8(src);
      *(f16x8*)&KbS[stg_row * 72 + stg_cq * 16 + 8] = cvt8(src + 8);
    }
    { // stage V transposed: pair-pack b32 writes, xor-swizzled (conflict ~2-way)
      const int g = lane >> 3;
#pragma unroll
      for (int i = 0; i < 8; ++i) {
        int bp = 8 * wave + (i ^ g);
        _Float16 h0 = (_Float16)Vn[(size_t)(k0 + 2*bp)     * HD + lane];
        _Float16 h1 = (_Float16)Vn[(size_t)(k0 + 2*bp + 1) * HD + lane];
        unsigned pk = (unsigned)__builtin_bit_cast(unsigned short, h0)
                    | ((unsigned)__builtin_bit_cast(unsigned short, h1) << 16);
        *(unsigned*)&VtS[lane * 72 + 2*bp] = pk;
      }
    }
    fill_band(k0 - a0 - 1);   // new 64 band columns (internal sync)

    // ---- content scores: D[q][key], wave owns q-rows [16w,16w+16) ----
    f32x4 sc[4];
#pragma unroll
    for (int ct = 0; ct < 4; ++ct) {
      f16x8 b0 = *(const f16x8*)&KbS[(16*ct + l15) * 72 + quad * 8];
      f16x8 b1 = *(const f16x8*)&KbS[(16*ct + l15) * 72 + 32 + quad * 8];
      f32x4 acc = (f32x4){0.f, 0.f, 0.f, 0.f};
      acc = MFMA16(quF[0], b0, acc);
      acc = MFMA16(quF[1], b1, acc);
      sc[ct] = acc;
    }
    __syncthreads();   // band writes visible

    // ---- gather + online softmax + stage P ----
    const int dlt = k0 - a0;
#pragma unroll
    for (int r = 0; r < 4; ++r) {
      const int ii = 16*wave + 4*quad + r;   // C-layout row = quad*4+reg
      float s[4];
#pragma unroll
      for (int ct = 0; ct < 4; ++ct) {
        const int cc = 16*ct + l15;
        const int e  = dlt + cc - ii;        // b - a
        const int u  = (e > 0) ? 1 : 0;
        const int slot = (e - 1 - u + 2048) & 127;
        float pos = Pb[(ii + u) * 132 + slot];
        s[ct] = sc[ct][r] + ((e == 1) ? 0.f : pos);
      }
      float mx = fmaxf(fmaxf(s[0], s[1]), fmaxf(s[2], s[3]));
#pragma unroll
      for (int off = 1; off < 16; off <<= 1) mx = fmaxf(mx, __shfl_xor(mx, off));
      const float mnew = fmaxf(mrow[r], mx);
      const float al   = __expf(mrow[r] - mnew);   // first iter: exp(-3e38) = 0
      mrow[r] = mnew;
      float p0 = __expf(s[0] - mnew), p1 = __expf(s[1] - mnew),
            p2 = __expf(s[2] - mnew), p3 = __expf(s[3] - mnew);
      float sum = (p0 + p1) + (p2 + p3);
#pragma unroll
      for (int off = 1; off < 16; off <<= 1) sum += __shfl_xor(sum, off);
      lrow[r] = lrow[r] * al + sum;
#pragma unroll
      for (int ct = 0; ct < 4; ++ct) Oacc[ct][r] *= al;
      const int pbase = wave * 1152 + (4*quad + r) * 72 + l15;
      PsS[pbase]      = (_Float16)p0;
      PsS[pbase + 16] = (_Float16)p1;
      PsS[pbase + 32] = (_Float16)p2;
      PsS[pbase + 48] = (_Float16)p3;
    }
    __syncthreads();   // Ps visible

    // ---- PV: O[q][d] += P[q][b] V[b][d] ----
    f16x8 pA0 = *(const f16x8*)&PsS[wave * 1152 + l15 * 72 + quad * 8];
    f16x8 pA1 = *(const f16x8*)&PsS[wave * 1152 + l15 * 72 + 32 + quad * 8];
#pragma unroll
    for (int ct = 0; ct < 4; ++ct) {
      f16x8 b0 = *(const f16x8*)&VtS[(16*ct + l15) * 72 + quad * 8];
      f16x8 b1 = *(const f16x8*)&VtS[(16*ct + l15) * 72 + 32 + quad * 8];
      Oacc[ct] = MFMA16(pA0, b0, Oacc[ct]);
      Oacc[ct] = MFMA16(pA1, b1, Oacc[ct]);
    }
  }

  // ---- epilogue ----
#pragma unroll
  for (int r = 0; r < 4; ++r) {
    const float inv = 1.f / lrow[r];
    const size_t rowo = (size_t)n * SQ * HD + (size_t)(a0 + 16*wave + 4*quad + r) * HD;
#pragma unroll
    for (int ct = 0; ct < 4; ++ct)
      O[rowo + 16*ct + l15] = Oacc[ct][r] * inv;
  }
}

extern "C" void kernel_launch(void* const* d_in, const int* in_sizes, int n_in,
                              void* d_out, int out_size, void* d_ws, size_t ws_size,
                              hipStream_t stream) {
  const float* Q  = (const float*)d_in[0];
  const float* K  = (const float*)d_in[1];
  const float* V  = (const float*)d_in[2];
  const float* Ub = (const float*)d_in[3];  // (1,16,1,64)
  const float* Vb = (const float*)d_in[4];
  const float* R  = (const float*)d_in[5];  // (16,2048,64)
  float* O = (float*)d_out;

  dim3 grid(64, 16);   // x = n (XCD locality), y = q-tile
  relpos_sdpa_mfma<<<grid, 256, 0, stream>>>(Q, K, V, Ub, Vb, R, O);
}